// Round 4
// baseline (365.635 us; speedup 1.0000x reference)
//
#include <hip/hip_runtime.h>
#include <math.h>

#define IMG_H 512
#define IMG_W 512
#define NCELL 64     // cells per dim (512/8)
#define NORI 9

// ---------------------------------------------------------------------------
// Bit-exact transcription of glibc/FDLIBM float atan / atan2 (flt-32 Sun code)
// — what numpy's np.arctan2 float32 loop resolves to on glibc <= 2.40.
// All arithmetic is plain IEEE f32 with contraction disabled.
// ---------------------------------------------------------------------------
__device__ __forceinline__ float fdlibm_atanf(float x) {
#pragma clang fp contract(off)
    const float atanhi[4] = {4.6364760399e-01f, 7.8539812565e-01f,
                             9.8279368877e-01f, 1.5707962513e+00f};
    const float atanlo[4] = {5.0121582440e-09f, 3.7748947079e-08f,
                             3.4473217170e-08f, 7.5497894159e-08f};
    const float aT[11] = {
        3.3333334327e-01f, -2.0000000298e-01f, 1.4285714924e-01f,
       -1.1111110449e-01f,  9.0908870101e-02f, -7.6918758452e-02f,
        6.6610731184e-02f, -5.8335702866e-02f,  4.9768779427e-02f,
       -3.6531571299e-02f,  1.6285819933e-02f};
    const float one = 1.0f;

    int hx = __float_as_int(x);
    int ix = hx & 0x7fffffff;
    int id;
    if (ix >= 0x4c800000) {                 // |x| >= 2^26
        if (hx > 0) return atanhi[3] + atanlo[3];
        else        return -atanhi[3] - atanlo[3];
    }
    if (ix < 0x3ee00000) {                  // |x| < 0.4375
        if (ix < 0x39800000) {              // |x| < 2^-12
            return x;
        }
        id = -1;
    } else {
        x = fabsf(x);
        if (ix < 0x3f980000) {              // |x| < 1.1875
            if (ix < 0x3f300000) { id = 0; x = (2.0f * x - one) / (2.0f + x); }
            else                 { id = 1; x = (x - one) / (x + one); }
        } else {
            if (ix < 0x401c0000) { id = 2; x = (x - 1.5f) / (one + 1.5f * x); }
            else                 { id = 3; x = -1.0f / x; }
        }
    }
    float z = x * x;
    float w = z * z;
    float s1 = z * (aT[0] + w * (aT[2] + w * (aT[4] + w * (aT[6] + w * (aT[8] + w * aT[10])))));
    float s2 = w * (aT[1] + w * (aT[3] + w * (aT[5] + w * (aT[7] + w * aT[9]))));
    if (id < 0) return x - x * (s1 + s2);
    z = atanhi[id] - ((x * (s1 + s2) - atanlo[id]) - x);
    return (hx < 0) ? -z : z;
}

__device__ __forceinline__ float fdlibm_atan2f(float y, float x) {
#pragma clang fp contract(off)
    const float tiny   = 1.0e-30f;
    const float pi_o_2 = 1.5707963705e+00f;   // 0x3FC90FDB
    const float pi     = 3.1415927410e+00f;   // 0x40490FDB
    const float pi_lo  = -8.7422776573e-08f;  // 0xB3BBBD2E

    int hx = __float_as_int(x), ix = hx & 0x7fffffff;
    int hy = __float_as_int(y), iy = hy & 0x7fffffff;
    if (hx == 0x3f800000) return fdlibm_atanf(y);          // x == 1.0
    int m = ((hy >> 31) & 1) | ((hx >> 30) & 2);           // 2*sign(x)+sign(y)

    if (iy == 0) {                                          // y == +-0
        switch (m) {
            case 0:
            case 1: return y;
            case 2: return  pi + tiny;
            case 3: return -pi - tiny;
        }
    }
    if (ix == 0) return (hy < 0) ? -pi_o_2 - tiny : pi_o_2 + tiny;  // x == +-0

    int k = (iy - ix) >> 23;
    float z;
    if (k > 26) {                                           // |y/x| > 2^26
        z = pi_o_2 + 0.5f * pi_lo;
        m &= 1;
    } else if (k < -26 && hx < 0) {
        z = 0.0f;
    } else {
        z = fdlibm_atanf(fabsf(y / x));
    }
    switch (m) {
        case 0:  return z;
        case 1:  return -z;
        case 2:  return pi - (z - pi_lo);
        default: return (z - pi_lo) - pi;
    }
}

// ---------------------------------------------------------------------------
// Kernel 1: per-cell orientation histograms.
// One block per (batch, cell-row). LDS-stages gray rows h0-1..h0+8 (10x512),
// one thread per pixel column (2 passes of 256 cols), LDS atomics into the
// 64-cell x 9-bin histogram, then writes hist/64 to global ws.
// Gray uses an explicit FMA chain: fmaf(b,w2, fmaf(g,w1, r*w0)) — matching
// numpy einsum's SIMD/-ffp-contract=fast accumulation (acc += x[c]*w[c]).
// ---------------------------------------------------------------------------
__global__ __launch_bounds__(256) void hog_hist_kernel(const float* __restrict__ x,
                                                       float* __restrict__ hist) {
#pragma clang fp contract(off)
    const int bid = blockIdx.x;
    const int b   = bid >> 6;     // batch
    const int cr  = bid & 63;     // cell row
    const int t   = threadIdx.x;
    const int h0  = cr * 8;

    __shared__ __align__(16) float g[10][IMG_W];       // 20 KB gray strip + halo rows
    __shared__ float cellHist[NCELL * NORI];           // 2.3 KB

    for (int i = t; i < NCELL * NORI; i += 256) cellHist[i] = 0.0f;

    // ---- load gray rows (float4-vectorized: 4 pixels = 3 float4 per group) ----
    const float GW0 = 0.2125f, GW1 = 0.7154f, GW2 = 0.0721f;
    for (int gi = t; gi < 10 * 128; gi += 256) {
        const int rr = gi >> 7;               // 0..9
        const int h  = h0 - 1 + rr;
        if (h < 0 || h >= IMG_H) continue;    // boundary rows never read (g_row=0 there)
        const int grp = gi & 127;             // 4-pixel group within row
        const float4* p4 = (const float4*)x + (size_t)(b * IMG_H + h) * (IMG_W * 3 / 4)
                           + (size_t)grp * 3;
        float4 a = p4[0], c = p4[1], d = p4[2];
        const int wg = grp * 4;
        // numpy einsum accumulation with FMA: fmaf(b,w2, fmaf(g,w1, r*w0))
        g[rr][wg + 0] = __builtin_fmaf(a.z, GW2, __builtin_fmaf(a.y, GW1, a.x * GW0));
        g[rr][wg + 1] = __builtin_fmaf(c.y, GW2, __builtin_fmaf(c.x, GW1, a.w * GW0));
        g[rr][wg + 2] = __builtin_fmaf(d.x, GW2, __builtin_fmaf(c.w, GW1, c.z * GW0));
        g[rr][wg + 3] = __builtin_fmaf(d.w, GW2, __builtin_fmaf(d.z, GW1, d.y * GW0));
    }
    __syncthreads();

    // ---- per-pixel gradient, magnitude, orientation bin ----
    const float RAD2DEG = (float)(180.0 / 3.14159265358979311600e+00);  // f32 rad2deg factor
    for (int pass = 0; pass < 2; ++pass) {
        const int w    = t + pass * 256;        // pixel column 0..511 (stride-1 -> no LDS conflicts)
        const int cell = w >> 3;
        for (int r = 0; r < 8; ++r) {
            const int h = h0 + r;
            float gr = 0.0f, gc = 0.0f;
            if (h >= 1 && h <= IMG_H - 2) gr = g[r + 2][w] - g[r][w];
            if (w >= 1 && w <= IMG_W - 2) gc = g[r + 1][w + 1] - g[r + 1][w - 1];
            const double dr = (double)gr, dc = (double)gc;
            const float mag = (float)sqrt(dr * dr + dc * dc);   // == CR hypotf (continuous path)
            const float th  = fdlibm_atan2f(gr, gc);            // == glibc<=2.40 atan2f, bit-exact
            float m = fmodf(th * RAD2DEG, 180.0f);              // numpy remainder semantics:
            if (m < 0.0f) m += 180.0f;                          // (can round up to exactly 180)
            int o = (int)(m * 0.05f);
            if (o < 9) {                                        // exact boundary fix-up
                if (m < 20.0f * (float)o) --o;
                else if (m >= 20.0f * (float)(o + 1)) ++o;
            }
            if (o >= 0 && o <= 8 && mag != 0.0f)
                atomicAdd(&cellHist[cell * NORI + o], mag);
        }
    }
    __syncthreads();

    float* hout = hist + (size_t)(b * NCELL + cr) * (NCELL * NORI);
    for (int i = t; i < NCELL * NORI; i += 256) hout[i] = cellHist[i] * 0.015625f; // /64
}

// ---------------------------------------------------------------------------
// Kernel 2: 2x2 block gathering + double L2-hys normalization.
// One block per (batch, block-row). 4 lanes per output block (one cell each),
// quad shfl_xor butterflies for the norms, LDS-staged coalesced output.
// ---------------------------------------------------------------------------
__global__ __launch_bounds__(256) void hog_norm_kernel(const float* __restrict__ hist,
                                                       float* __restrict__ out) {
#pragma clang fp contract(off)
    const int bid = blockIdx.x;
    const int b   = bid / 63;
    const int r   = bid % 63;
    const int t   = threadIdx.x;

    __shared__ __align__(16) float hrow[2 * NCELL * NORI];  // hist rows r, r+1 (1152 floats)
    __shared__ __align__(16) float orow[63 * 36];           // 2268 floats staged output

    const float4* src = (const float4*)(hist + (size_t)(b * NCELL + r) * (NCELL * NORI));
    float4* dst = (float4*)hrow;
    for (int i = t; i < 288; i += 256) dst[i] = src[i];     // 2 rows x 144 float4, contiguous
    __syncthreads();

    const int c = t >> 2;      // block column 0..63 (63 used)
    const int l = t & 3;       // (i,j) within 2x2
    if (c < 63) {
        const int bi = l >> 1, bj = l & 1;
        const float* v = &hrow[(bi * NCELL + (c + bj)) * NORI];
        float vv[9];
        float ss = 0.0f;
#pragma unroll
        for (int k = 0; k < 9; ++k) { vv[k] = v[k]; ss += vv[k] * vv[k]; }
        ss += __shfl_xor(ss, 1, 64);
        ss += __shfl_xor(ss, 2, 64);
        const float n1 = sqrtf(ss + 1e-10f);                // EPS^2 = 1e-10
        float ss2 = 0.0f;
#pragma unroll
        for (int k = 0; k < 9; ++k) { vv[k] = fminf(vv[k] / n1, 0.2f); ss2 += vv[k] * vv[k]; }
        ss2 += __shfl_xor(ss2, 1, 64);
        ss2 += __shfl_xor(ss2, 2, 64);
        const float n2 = sqrtf(ss2 + 1e-10f);
        float* od = &orow[c * 36 + l * 9];
#pragma unroll
        for (int k = 0; k < 9; ++k) od[k] = vv[k] / n2;
    }
    __syncthreads();

    float4* og = (float4*)(out + (size_t)bid * (63 * 36));
    const float4* os = (const float4*)orow;
    for (int i = t; i < 567; i += 256) og[i] = os[i];       // 2268 floats = 567 float4
}

extern "C" void kernel_launch(void* const* d_in, const int* in_sizes, int n_in,
                              void* d_out, int out_size, void* d_ws, size_t ws_size,
                              hipStream_t stream) {
    const float* x = (const float*)d_in[0];
    float* out     = (float*)d_out;
    float* hist    = (float*)d_ws;   // 64*64*64*9 floats = 9.4 MB scratch

    hog_hist_kernel<<<dim3(64 * 64), dim3(256), 0, stream>>>(x, hist);
    hog_norm_kernel<<<dim3(64 * 63), dim3(256), 0, stream>>>(hist, out);
}

// Round 5
// 336.507 us; speedup vs baseline: 1.0866x; 1.0866x over previous
//
#include <hip/hip_runtime.h>
#include <math.h>

#define IMG_H 512
#define IMG_W 512
#define NCELL 64     // cells per dim (512/8)
#define NORI 9

// ---------------------------------------------------------------------------
// Bit-exact transcription of glibc/FDLIBM float atan / atan2 (flt-32 Sun code)
// — what numpy's np.arctan2 float32 loop resolves to on glibc <= 2.40.
// Used ONLY for pixels near a bin boundary (slow path, ~2e-4 of pixels).
// ---------------------------------------------------------------------------
__device__ __noinline__ float fdlibm_atanf(float x) {
#pragma clang fp contract(off)
    const float atanhi[4] = {4.6364760399e-01f, 7.8539812565e-01f,
                             9.8279368877e-01f, 1.5707962513e+00f};
    const float atanlo[4] = {5.0121582440e-09f, 3.7748947079e-08f,
                             3.4473217170e-08f, 7.5497894159e-08f};
    const float aT[11] = {
        3.3333334327e-01f, -2.0000000298e-01f, 1.4285714924e-01f,
       -1.1111110449e-01f,  9.0908870101e-02f, -7.6918758452e-02f,
        6.6610731184e-02f, -5.8335702866e-02f,  4.9768779427e-02f,
       -3.6531571299e-02f,  1.6285819933e-02f};
    const float one = 1.0f;

    int hx = __float_as_int(x);
    int ix = hx & 0x7fffffff;
    int id;
    if (ix >= 0x4c800000) {                 // |x| >= 2^26
        if (hx > 0) return atanhi[3] + atanlo[3];
        else        return -atanhi[3] - atanlo[3];
    }
    if (ix < 0x3ee00000) {                  // |x| < 0.4375
        if (ix < 0x39800000) {              // |x| < 2^-12
            return x;
        }
        id = -1;
    } else {
        x = fabsf(x);
        if (ix < 0x3f980000) {              // |x| < 1.1875
            if (ix < 0x3f300000) { id = 0; x = (2.0f * x - one) / (2.0f + x); }
            else                 { id = 1; x = (x - one) / (x + one); }
        } else {
            if (ix < 0x401c0000) { id = 2; x = (x - 1.5f) / (one + 1.5f * x); }
            else                 { id = 3; x = -1.0f / x; }
        }
    }
    float z = x * x;
    float w = z * z;
    float s1 = z * (aT[0] + w * (aT[2] + w * (aT[4] + w * (aT[6] + w * (aT[8] + w * aT[10])))));
    float s2 = w * (aT[1] + w * (aT[3] + w * (aT[5] + w * (aT[7] + w * aT[9]))));
    if (id < 0) return x - x * (s1 + s2);
    z = atanhi[id] - ((x * (s1 + s2) - atanlo[id]) - x);
    return (hx < 0) ? -z : z;
}

__device__ __noinline__ int fdlibm_bin(float y, float x) {
#pragma clang fp contract(off)
    // exact reference chain: fdlibm atan2f -> f32 rad2deg -> numpy mod -> bin
    const float tiny   = 1.0e-30f;
    const float pi_o_2 = 1.5707963705e+00f;   // 0x3FC90FDB
    const float pi     = 3.1415927410e+00f;   // 0x40490FDB
    const float pi_lo  = -8.7422776573e-08f;  // 0xB3BBBD2E

    int hx = __float_as_int(x), ix = hx & 0x7fffffff;
    int hy = __float_as_int(y), iy = hy & 0x7fffffff;
    float th;
    if (hx == 0x3f800000) { th = fdlibm_atanf(y); }        // x == 1.0
    else {
        int m = ((hy >> 31) & 1) | ((hx >> 30) & 2);       // 2*sign(x)+sign(y)
        if (iy == 0) {                                      // y == +-0
            switch (m) {
                case 0:
                case 1: th = y; break;
                case 2: th =  pi + tiny; break;
                default: th = -pi - tiny; break;
            }
        } else if (ix == 0) {
            th = (hy < 0) ? -pi_o_2 - tiny : pi_o_2 + tiny; // x == +-0
        } else {
            int k = (iy - ix) >> 23;
            float z;
            int mm = m;
            if (k > 26) {                                   // |y/x| > 2^26
                z = pi_o_2 + 0.5f * pi_lo;
                mm &= 1;
            } else if (k < -26 && hx < 0) {
                z = 0.0f;
            } else {
                z = fdlibm_atanf(fabsf(y / x));
            }
            switch (mm) {
                case 0:  th = z; break;
                case 1:  th = -z; break;
                case 2:  th = pi - (z - pi_lo); break;
                default: th = (z - pi_lo) - pi; break;
            }
        }
    }
    const float RAD2DEG = (float)(180.0 / 3.14159265358979311600e+00);
    float m = fmodf(th * RAD2DEG, 180.0f);                  // numpy remainder semantics
    if (m < 0.0f) m += 180.0f;                              // (can round up to exactly 180)
    int o = (int)(m * 0.05f);
    if (o < 9) {                                            // exact boundary fix-up
        if (m < 20.0f * (float)o) --o;
        else if (m >= 20.0f * (float)(o + 1)) ++o;
    }
    return o;                                               // may be 9 (== exactly 180): no bin
}

// ---------------------------------------------------------------------------
// Kernel 1: per-cell orientation histograms.
// Fast path: 1 divide + Cephes 4-term atan poly (rel err 2.4e-8) + quadrant
// selects -> bin; pixels within 1e-4 bin-fraction (2e-3 deg) of a boundary
// (~2e-4 of pixels) re-bin through the exact FDLIBM chain, guaranteeing
// bit-identical bin decisions vs the f32 numpy reference.
// Gray uses the FMA chain fmaf(b,w2, fmaf(g,w1, r*w0)) — matches numpy
// einsum's FMA accumulation (verified round 4).
// ---------------------------------------------------------------------------
__global__ __launch_bounds__(256) void hog_hist_kernel(const float* __restrict__ x,
                                                       float* __restrict__ hist) {
#pragma clang fp contract(off)
    const int bid = blockIdx.x;
    const int b   = bid >> 6;     // batch
    const int cr  = bid & 63;     // cell row
    const int t   = threadIdx.x;
    const int h0  = cr * 8;

    __shared__ __align__(16) float g[10][IMG_W];       // 20 KB gray strip + halo rows
    __shared__ float cellHist[NCELL * NORI];           // 2.3 KB

    for (int i = t; i < NCELL * NORI; i += 256) cellHist[i] = 0.0f;

    // ---- load gray rows (float4-vectorized: 4 pixels = 3 float4 per group) ----
    const float GW0 = 0.2125f, GW1 = 0.7154f, GW2 = 0.0721f;
    for (int gi = t; gi < 10 * 128; gi += 256) {
        const int rr = gi >> 7;               // 0..9
        const int h  = h0 - 1 + rr;
        if (h < 0 || h >= IMG_H) continue;    // boundary rows never read (g_row=0 there)
        const int grp = gi & 127;             // 4-pixel group within row
        const float4* p4 = (const float4*)x + (size_t)(b * IMG_H + h) * (IMG_W * 3 / 4)
                           + (size_t)grp * 3;
        float4 a = p4[0], c = p4[1], d = p4[2];
        const int wg = grp * 4;
        g[rr][wg + 0] = __builtin_fmaf(a.z, GW2, __builtin_fmaf(a.y, GW1, a.x * GW0));
        g[rr][wg + 1] = __builtin_fmaf(c.y, GW2, __builtin_fmaf(c.x, GW1, a.w * GW0));
        g[rr][wg + 2] = __builtin_fmaf(d.x, GW2, __builtin_fmaf(c.w, GW1, c.z * GW0));
        g[rr][wg + 3] = __builtin_fmaf(d.w, GW2, __builtin_fmaf(d.z, GW1, d.y * GW0));
    }
    __syncthreads();

    // ---- per-pixel gradient, magnitude, orientation bin ----
    const float PIF   = 3.14159265358979323846f;
    const float PIO2F = 1.57079632679489662f;
    const float PIO4F = 0.78539816339744831f;
    for (int pass = 0; pass < 2; ++pass) {
        const int w    = t + pass * 256;        // pixel column 0..511 (stride-1 LDS, no conflicts)
        const int cell = w >> 3;
        for (int r = 0; r < 8; ++r) {
            const int h = h0 + r;
            float gr = 0.0f, gc = 0.0f;
            if (h >= 1 && h <= IMG_H - 2) gr = g[r + 2][w] - g[r][w];
            if (w >= 1 && w <= IMG_W - 2) gc = g[r + 1][w + 1] - g[r + 1][w - 1];
            const float mag = sqrtf(__builtin_fmaf(gr, gr, gc * gc));  // continuous path: f32 ok
            if (mag == 0.0f) continue;

            // fast octant-reduced atan: red <=> mn/mx > tan(pi/8), fused into one divide
            const float ax = fabsf(gc), ay = fabsf(gr);
            const float mx = fmaxf(ax, ay), mn = fminf(ax, ay);
            const bool red = mn > 0.4142135624f * mx;
            const float num = red ? (mn - mx) : mn;
            const float den = red ? (mn + mx) : mx;
            const float xx  = num / den;                    // in [-0.4142, 0.4142]
            const float z   = xx * xx;
            // Cephes atanf minimax, |x|<=0.4142: rel err ~2.4e-8
            float y = __builtin_fmaf(
                        __builtin_fmaf(
                          __builtin_fmaf(8.05374449538e-2f, z, -1.38776856032e-1f),
                          z, 1.99777106478e-1f),
                        z, -3.33329491539e-1f);
            float r0 = __builtin_fmaf(y * z, xx, xx);       // atan(xx)
            if (red)        r0 = PIO4F + r0;                // atan(mn/mx) in [0, pi/4]
            if (ay > ax)    r0 = PIO2F - r0;                // atan2(ay, ax) in [0, pi/2]
            if (gc < 0.0f)  r0 = PIF - r0;                  // angle of (gc, ay) in [0, pi]
            if (gr < 0.0f)  r0 = PIF - r0;                  // theta mod pi
            const float q    = (r0 * 57.295779513082323f) * 0.05f;   // bin coordinate
            int o            = (int)q;
            const float frac = q - (float)o;
            if (frac < 1e-4f || frac > 0.9999f || o > 8) {  // near boundary: exact chain
                o = fdlibm_bin(gr, gc);
                if (o < 0 || o > 8) continue;               // exactly-180 edge: no bin
            }
            atomicAdd(&cellHist[cell * NORI + o], mag);
        }
    }
    __syncthreads();

    float* hout = hist + (size_t)(b * NCELL + cr) * (NCELL * NORI);
    for (int i = t; i < NCELL * NORI; i += 256) hout[i] = cellHist[i] * 0.015625f; // /64
}

// ---------------------------------------------------------------------------
// Kernel 2: 2x2 block gathering + double L2-hys normalization.
// One block per (batch, block-row). 4 lanes per output block (one cell each),
// quad shfl_xor butterflies for the norms, LDS-staged coalesced output.
// ---------------------------------------------------------------------------
__global__ __launch_bounds__(256) void hog_norm_kernel(const float* __restrict__ hist,
                                                       float* __restrict__ out) {
#pragma clang fp contract(off)
    const int bid = blockIdx.x;
    const int b   = bid / 63;
    const int r   = bid % 63;
    const int t   = threadIdx.x;

    __shared__ __align__(16) float hrow[2 * NCELL * NORI];  // hist rows r, r+1 (1152 floats)
    __shared__ __align__(16) float orow[63 * 36];           // 2268 floats staged output

    const float4* src = (const float4*)(hist + (size_t)(b * NCELL + r) * (NCELL * NORI));
    float4* dst = (float4*)hrow;
    for (int i = t; i < 288; i += 256) dst[i] = src[i];     // 2 rows x 144 float4, contiguous
    __syncthreads();

    const int c = t >> 2;      // block column 0..63 (63 used)
    const int l = t & 3;       // (i,j) within 2x2
    if (c < 63) {
        const int bi = l >> 1, bj = l & 1;
        const float* v = &hrow[(bi * NCELL + (c + bj)) * NORI];
        float vv[9];
        float ss = 0.0f;
#pragma unroll
        for (int k = 0; k < 9; ++k) { vv[k] = v[k]; ss += vv[k] * vv[k]; }
        ss += __shfl_xor(ss, 1, 64);
        ss += __shfl_xor(ss, 2, 64);
        const float n1 = sqrtf(ss + 1e-10f);                // EPS^2 = 1e-10
        float ss2 = 0.0f;
#pragma unroll
        for (int k = 0; k < 9; ++k) { vv[k] = fminf(vv[k] / n1, 0.2f); ss2 += vv[k] * vv[k]; }
        ss2 += __shfl_xor(ss2, 1, 64);
        ss2 += __shfl_xor(ss2, 2, 64);
        const float n2 = sqrtf(ss2 + 1e-10f);
        float* od = &orow[c * 36 + l * 9];
#pragma unroll
        for (int k = 0; k < 9; ++k) od[k] = vv[k] / n2;
    }
    __syncthreads();

    float4* og = (float4*)(out + (size_t)bid * (63 * 36));
    const float4* os = (const float4*)orow;
    for (int i = t; i < 567; i += 256) og[i] = os[i];       // 2268 floats = 567 float4
}

extern "C" void kernel_launch(void* const* d_in, const int* in_sizes, int n_in,
                              void* d_out, int out_size, void* d_ws, size_t ws_size,
                              hipStream_t stream) {
    const float* x = (const float*)d_in[0];
    float* out     = (float*)d_out;
    float* hist    = (float*)d_ws;   // 64*64*64*9 floats = 9.4 MB scratch

    hog_hist_kernel<<<dim3(64 * 64), dim3(256), 0, stream>>>(x, hist);
    hog_norm_kernel<<<dim3(64 * 63), dim3(256), 0, stream>>>(hist, out);
}

// Round 6
// 336.335 us; speedup vs baseline: 1.0871x; 1.0005x over previous
//
#include <hip/hip_runtime.h>
#include <math.h>

#define IMG_H 512
#define IMG_W 512
#define NCELL 64     // cells per dim (512/8)
#define NORI 9

// ---------------------------------------------------------------------------
// Bit-exact transcription of glibc/FDLIBM float atan / atan2 (flt-32 Sun code)
// — what numpy's np.arctan2 float32 loop resolves to on glibc <= 2.40.
// Used ONLY for pixels near a bin boundary (slow path, ~2e-4 of pixels,
// plus the structural gr==0 rows 0/511 which land exactly on a boundary).
// ---------------------------------------------------------------------------
__device__ __noinline__ float fdlibm_atanf(float x) {
#pragma clang fp contract(off)
    const float atanhi[4] = {4.6364760399e-01f, 7.8539812565e-01f,
                             9.8279368877e-01f, 1.5707962513e+00f};
    const float atanlo[4] = {5.0121582440e-09f, 3.7748947079e-08f,
                             3.4473217170e-08f, 7.5497894159e-08f};
    const float aT[11] = {
        3.3333334327e-01f, -2.0000000298e-01f, 1.4285714924e-01f,
       -1.1111110449e-01f,  9.0908870101e-02f, -7.6918758452e-02f,
        6.6610731184e-02f, -5.8335702866e-02f,  4.9768779427e-02f,
       -3.6531571299e-02f,  1.6285819933e-02f};
    const float one = 1.0f;

    int hx = __float_as_int(x);
    int ix = hx & 0x7fffffff;
    int id;
    if (ix >= 0x4c800000) {                 // |x| >= 2^26
        if (hx > 0) return atanhi[3] + atanlo[3];
        else        return -atanhi[3] - atanlo[3];
    }
    if (ix < 0x3ee00000) {                  // |x| < 0.4375
        if (ix < 0x39800000) {              // |x| < 2^-12
            return x;
        }
        id = -1;
    } else {
        x = fabsf(x);
        if (ix < 0x3f980000) {              // |x| < 1.1875
            if (ix < 0x3f300000) { id = 0; x = (2.0f * x - one) / (2.0f + x); }
            else                 { id = 1; x = (x - one) / (x + one); }
        } else {
            if (ix < 0x401c0000) { id = 2; x = (x - 1.5f) / (one + 1.5f * x); }
            else                 { id = 3; x = -1.0f / x; }
        }
    }
    float z = x * x;
    float w = z * z;
    float s1 = z * (aT[0] + w * (aT[2] + w * (aT[4] + w * (aT[6] + w * (aT[8] + w * aT[10])))));
    float s2 = w * (aT[1] + w * (aT[3] + w * (aT[5] + w * (aT[7] + w * aT[9]))));
    if (id < 0) return x - x * (s1 + s2);
    z = atanhi[id] - ((x * (s1 + s2) - atanlo[id]) - x);
    return (hx < 0) ? -z : z;
}

__device__ __noinline__ int fdlibm_bin(float y, float x) {
#pragma clang fp contract(off)
    // exact reference chain: fdlibm atan2f -> f32 rad2deg -> numpy mod -> bin
    const float tiny   = 1.0e-30f;
    const float pi_o_2 = 1.5707963705e+00f;   // 0x3FC90FDB
    const float pi     = 3.1415927410e+00f;   // 0x40490FDB
    const float pi_lo  = -8.7422776573e-08f;  // 0xB3BBBD2E

    int hx = __float_as_int(x), ix = hx & 0x7fffffff;
    int hy = __float_as_int(y), iy = hy & 0x7fffffff;
    float th;
    if (hx == 0x3f800000) { th = fdlibm_atanf(y); }        // x == 1.0
    else {
        int m = ((hy >> 31) & 1) | ((hx >> 30) & 2);       // 2*sign(x)+sign(y)
        if (iy == 0) {                                      // y == +-0
            switch (m) {
                case 0:
                case 1: th = y; break;
                case 2: th =  pi + tiny; break;
                default: th = -pi - tiny; break;
            }
        } else if (ix == 0) {
            th = (hy < 0) ? -pi_o_2 - tiny : pi_o_2 + tiny; // x == +-0
        } else {
            int k = (iy - ix) >> 23;
            float z;
            int mm = m;
            if (k > 26) {                                   // |y/x| > 2^26
                z = pi_o_2 + 0.5f * pi_lo;
                mm &= 1;
            } else if (k < -26 && hx < 0) {
                z = 0.0f;
            } else {
                z = fdlibm_atanf(fabsf(y / x));
            }
            switch (mm) {
                case 0:  th = z; break;
                case 1:  th = -z; break;
                case 2:  th = pi - (z - pi_lo); break;
                default: th = (z - pi_lo) - pi; break;
            }
        }
    }
    const float RAD2DEG = (float)(180.0 / 3.14159265358979311600e+00);
    float m = fmodf(th * RAD2DEG, 180.0f);                  // numpy remainder semantics
    if (m < 0.0f) m += 180.0f;                              // (can round up to exactly 180)
    int o = (int)(m * 0.05f);
    if (o < 9) {                                            // exact boundary fix-up
        if (m < 20.0f * (float)o) --o;
        else if (m >= 20.0f * (float)(o + 1)) ++o;
    }
    return o;                                               // may be 9 (== exactly 180): no bin
}

// ---------------------------------------------------------------------------
// Kernel 1: per-cell orientation histograms.
// Latency-optimized: mirror-halo staging kills all h-bounds checks (gr is
// exactly +0.0 at rows 0/511 by construction); each lane batch-preloads its
// 26 LDS values (10 center + 8 east + 8 west) into registers before the
// unrolled row loop (one latency exposure, not 8 dependent stalls); raw
// v_rcp_f32 / v_sqrt_f32 replace IEEE div/sqrt expansions (error << guard).
// Gray: FMA chain fmaf(b,w2, fmaf(g,w1, r*w0)) — verified vs numpy round 4.
// ---------------------------------------------------------------------------
__global__ __launch_bounds__(256) void hog_hist_kernel(const float* __restrict__ x,
                                                       float* __restrict__ hist) {
#pragma clang fp contract(off)
    const int bid = blockIdx.x;
    const int b   = bid >> 6;     // batch
    const int cr  = bid & 63;     // cell row
    const int t   = threadIdx.x;
    const int h0  = cr * 8;

    __shared__ __align__(16) float g[10][IMG_W];       // 20 KB gray strip + halo rows
    __shared__ float cellHist[NCELL * NORI];           // 2.3 KB

    for (int i = t; i < NCELL * NORI; i += 256) cellHist[i] = 0.0f;

    // ---- stage gray rows; halo rows MIRRORED so edge gr == +0.0 exactly ----
    const float GW0 = 0.2125f, GW1 = 0.7154f, GW2 = 0.0721f;
    for (int gi = t; gi < 10 * 128; gi += 256) {
        const int rr = gi >> 7;               // 0..9
        int h = h0 - 1 + rr;
        if (h < 0)      h = 1;                // g[0]:=gray(row1)=g[2] -> gr=0 at h=0
        if (h > 511)    h = 510;              // g[9]:=gray(row510)=g[7] -> gr=0 at h=511
        const int grp = gi & 127;             // 4-pixel group within row
        const float4* p4 = (const float4*)x + (size_t)(b * IMG_H + h) * (IMG_W * 3 / 4)
                           + (size_t)grp * 3;
        float4 a = p4[0], c = p4[1], d = p4[2];
        const int wg = grp * 4;
        g[rr][wg + 0] = __builtin_fmaf(a.z, GW2, __builtin_fmaf(a.y, GW1, a.x * GW0));
        g[rr][wg + 1] = __builtin_fmaf(c.y, GW2, __builtin_fmaf(c.x, GW1, a.w * GW0));
        g[rr][wg + 2] = __builtin_fmaf(d.x, GW2, __builtin_fmaf(c.w, GW1, c.z * GW0));
        g[rr][wg + 3] = __builtin_fmaf(d.w, GW2, __builtin_fmaf(d.z, GW1, d.y * GW0));
    }
    __syncthreads();

    // ---- per-pixel gradient, magnitude, orientation bin ----
    const float PIF   = 3.14159265358979323846f;
    const float PIO2F = 1.57079632679489662f;
    const float PIO4F = 0.78539816339744831f;
    for (int pass = 0; pass < 2; ++pass) {
        const int w  = t + pass * 256;          // pixel column 0..511 (stride-1 LDS)
        const int wl = (w == 0)   ? 0   : w - 1;
        const int wr = (w == 511) ? 511 : w + 1;
        const bool wok = (w >= 1) && (w <= 510);
        const int cellBase = (w >> 3) * NORI;

        // batch-preload: all independent ds_reads issued up front
        float cc[10], ee[8], ww[8];
#pragma unroll
        for (int i = 0; i < 10; ++i) cc[i] = g[i][w];
#pragma unroll
        for (int i = 0; i < 8; ++i) { ee[i] = g[i + 1][wr]; ww[i] = g[i + 1][wl]; }

#pragma unroll
        for (int r = 0; r < 8; ++r) {
            const float gr = cc[r + 2] - cc[r];              // +0.0 at image edge rows
            const float gc = wok ? (ee[r] - ww[r]) : 0.0f;
            const float mag = __builtin_amdgcn_sqrtf(__builtin_fmaf(gr, gr, gc * gc));

            // fast octant-reduced atan: red <=> mn/mx > tan(pi/8), one rcp
            const float ax = fabsf(gc), ay = fabsf(gr);
            const float mx = fmaxf(ax, ay), mn = fminf(ax, ay);
            const bool red = mn > 0.4142135624f * mx;
            const float num = red ? (mn - mx) : mn;
            const float den = red ? (mn + mx) : mx;
            const float xx  = num * __builtin_amdgcn_rcpf(den);  // 1-ulp rcp: err << guard
            const float z   = xx * xx;
            // Cephes atanf minimax, |x|<=0.4142: rel err ~2.4e-8
            float y = __builtin_fmaf(
                        __builtin_fmaf(
                          __builtin_fmaf(8.05374449538e-2f, z, -1.38776856032e-1f),
                          z, 1.99777106478e-1f),
                        z, -3.33329491539e-1f);
            float r0 = __builtin_fmaf(y * z, xx, xx);       // atan(xx)
            if (red)        r0 = PIO4F + r0;                // atan(mn/mx) in [0, pi/4]
            if (ay > ax)    r0 = PIO2F - r0;                // atan2(ay, ax) in [0, pi/2]
            if (gc < 0.0f)  r0 = PIF - r0;                  // angle of (gc, ay) in [0, pi]
            if (gr < 0.0f)  r0 = PIF - r0;                  // theta mod pi
            const float q    = (r0 * 57.295779513082323f) * 0.05f;   // bin coordinate
            int o            = (int)q;                      // (int)NaN==0 on gfx950: safe
            const float frac = q - (float)o;
            if (frac < 1e-4f || frac > 0.9999f || o > 8) {  // near boundary: exact chain
                o = fdlibm_bin(gr, gc);
                if (o < 0 || o > 8) continue;               // exactly-180 edge: no bin
            }
            atomicAdd(&cellHist[cellBase + o], mag);        // mag==0 adds +0.0: harmless
        }
    }
    __syncthreads();

    float* hout = hist + (size_t)(b * NCELL + cr) * (NCELL * NORI);
    for (int i = t; i < NCELL * NORI; i += 256) hout[i] = cellHist[i] * 0.015625f; // /64
}

// ---------------------------------------------------------------------------
// Kernel 2: 2x2 block gathering + double L2-hys normalization.
// One block per (batch, block-row). 4 lanes per output block (one cell each),
// quad shfl_xor butterflies for the norms, LDS-staged coalesced output.
// ---------------------------------------------------------------------------
__global__ __launch_bounds__(256) void hog_norm_kernel(const float* __restrict__ hist,
                                                       float* __restrict__ out) {
#pragma clang fp contract(off)
    const int bid = blockIdx.x;
    const int b   = bid / 63;
    const int r   = bid % 63;
    const int t   = threadIdx.x;

    __shared__ __align__(16) float hrow[2 * NCELL * NORI];  // hist rows r, r+1 (1152 floats)
    __shared__ __align__(16) float orow[63 * 36];           // 2268 floats staged output

    const float4* src = (const float4*)(hist + (size_t)(b * NCELL + r) * (NCELL * NORI));
    float4* dst = (float4*)hrow;
    for (int i = t; i < 288; i += 256) dst[i] = src[i];     // 2 rows x 144 float4, contiguous
    __syncthreads();

    const int c = t >> 2;      // block column 0..63 (63 used)
    const int l = t & 3;       // (i,j) within 2x2
    if (c < 63) {
        const int bi = l >> 1, bj = l & 1;
        const float* v = &hrow[(bi * NCELL + (c + bj)) * NORI];
        float vv[9];
        float ss = 0.0f;
#pragma unroll
        for (int k = 0; k < 9; ++k) { vv[k] = v[k]; ss += vv[k] * vv[k]; }
        ss += __shfl_xor(ss, 1, 64);
        ss += __shfl_xor(ss, 2, 64);
        const float n1 = sqrtf(ss + 1e-10f);                // EPS^2 = 1e-10
        float ss2 = 0.0f;
#pragma unroll
        for (int k = 0; k < 9; ++k) { vv[k] = fminf(vv[k] / n1, 0.2f); ss2 += vv[k] * vv[k]; }
        ss2 += __shfl_xor(ss2, 1, 64);
        ss2 += __shfl_xor(ss2, 2, 64);
        const float n2 = sqrtf(ss2 + 1e-10f);
        float* od = &orow[c * 36 + l * 9];
#pragma unroll
        for (int k = 0; k < 9; ++k) od[k] = vv[k] / n2;
    }
    __syncthreads();

    float4* og = (float4*)(out + (size_t)bid * (63 * 36));
    const float4* os = (const float4*)orow;
    for (int i = t; i < 567; i += 256) og[i] = os[i];       // 2268 floats = 567 float4
}

extern "C" void kernel_launch(void* const* d_in, const int* in_sizes, int n_in,
                              void* d_out, int out_size, void* d_ws, size_t ws_size,
                              hipStream_t stream) {
    const float* x = (const float*)d_in[0];
    float* out     = (float*)d_out;
    float* hist    = (float*)d_ws;   // 64*64*64*9 floats = 9.4 MB scratch

    hog_hist_kernel<<<dim3(64 * 64), dim3(256), 0, stream>>>(x, hist);
    hog_norm_kernel<<<dim3(64 * 63), dim3(256), 0, stream>>>(hist, out);
}